// Round 4
// baseline (378.183 us; speedup 1.0000x reference)
//
#include <hip/hip_runtime.h>

// MiniTransformer: B=131072, T=8, D=32, H=64, V=27  (all f32, out f32)
// R10: R9 + weight loads forced onto the SCALAR pipe via address_space(4).
//   R9 counters: fused_main 243us, VALUBusy 55% => ~15.5k VALU instr/wave
//   vs ~5.5k required FMA. The ~10k overhead = per-lane 64-bit address
//   arithmetic for ~3.4k weight loads whose addresses are WAVE-UNIFORM
//   (kernel-arg base + compile-time offset). Fix (CK's trick): cast W1/W2/
//   Wout to __attribute__((address_space(4))) through a uintptr round-trip
//   => loads are invariant+uniform => s_load_dwordx16 streams into SGPRs,
//   FMAs read the SGPR operand directly (v_fmac v,s,v). Removes the VMEM
//   instrs, the address VALU, and the VGPR pressure that caused ~23-slot
//   scratch spills (WRITE 131MB vs 70MB output).
//   R8 lesson kept: no __launch_bounds__ min-waves games.

namespace {
constexpr int BTOT = 131072;     // 2^17
constexpr int T = 8;
constexpr int D = 32;
constexpr int H = 64;
constexpr int V = 27;
constexpr int NTOK = 27;
constexpr int NROW = T * NTOK;   // 216
constexpr float EPS = 1e-5f;

// ws layout (float offsets)
constexpr int WS_X  = 0;             // 216*32
constexpr int WS_Q  = 6912;
constexpr int WS_K  = 13824;
constexpr int WS_V  = 20736;
constexpr int WS_SC = 27648;         // 216*216 = 46656
constexpr int NSC   = NROW * NROW;
constexpr int WS_P  = WS_SC + NSC;   // 74304: prefix-output tables
constexpr int NPRE0 = 27;
constexpr int NPRE1 = 729;
constexpr int NPRE2 = 19683;
constexpr int NPRE  = NPRE0 + NPRE1 + NPRE2;   // 20439
constexpr size_t WS_NEED_BIG = (size_t)(WS_P + NPRE * V) * 4;  // ~2.45 MB

constexpr int MAIN_BLOCKS = (5 * BTOT) / 256;          // 2560, exact
constexpr int PRE_BLOCKS  = (NPRE + 255) / 256;        // 80
} // namespace

// Constant-address-space pointer: loads from AS(4) are invariant by
// definition; with uniform addresses the backend emits s_load (SMEM),
// zero VALU / zero VGPR cost. Cast goes through uintptr (CK idiom) since
// direct pointer casts across address spaces are rejected by clang.
#define CONSTANT_AS __attribute__((address_space(4)))
typedef const CONSTANT_AS float cfloat;
__device__ __forceinline__ cfloat* to_const(const float* p) {
  return (cfloat*)(unsigned long long)p;
}

// ---- kernel A: X/Q/K/V row tables, thread per (row,d) ----
__global__ __launch_bounds__(256) void build_rows_kernel(
    const float* __restrict__ tokE, const float* __restrict__ posE,
    const float* __restrict__ Wq, const float* __restrict__ Wk,
    const float* __restrict__ Wv, float* __restrict__ ws) {
  const int idx = blockIdx.x * 256 + threadIdx.x;
  if (idx >= NROW * D) return;
  const int row = idx >> 5, d = idx & 31;
  const int t = row / NTOK, tok = row % NTOK;
  float x[D];
#pragma unroll
  for (int g = 0; g < D / 4; ++g) {
    const float4 a = *(const float4*)(tokE + tok * D + 4 * g);
    const float4 c = *(const float4*)(posE + t * D + 4 * g);
    x[4 * g + 0] = a.x + c.x;
    x[4 * g + 1] = a.y + c.y;
    x[4 * g + 2] = a.z + c.z;
    x[4 * g + 3] = a.w + c.w;
  }
  float aq = 0.f, ak = 0.f, av = 0.f;
#pragma unroll
  for (int k = 0; k < D; ++k) {
    const float xv = x[k];
    aq = fmaf(xv, Wq[k * D + d], aq);
    ak = fmaf(xv, Wk[k * D + d], ak);
    av = fmaf(xv, Wv[k * D + d], av);
  }
  ws[WS_X + row * D + d] = x[d];
  ws[WS_Q + row * D + d] = aq;
  ws[WS_K + row * D + d] = ak;
  ws[WS_V + row * D + d] = av;
}

// ---- kernel B: score table SC[(t*27+tokt)*216 + s*27+toks] ----
__global__ __launch_bounds__(256) void build_sc_kernel(float* __restrict__ ws) {
  const int i = blockIdx.x * 256 + threadIdx.x;
  if (i >= NSC) return;
  const int qrow = i / NROW;
  const int j    = i - qrow * NROW;
  const float4* q = (const float4*)(ws + WS_Q + qrow * D);
  const float4* k = (const float4*)(ws + WS_K + j * D);
  float a = 0.f;
#pragma unroll
  for (int g = 0; g < D / 4; ++g) {
    const float4 qa = q[g], ka = k[g];
    a = fmaf(qa.x, ka.x, a);
    a = fmaf(qa.y, ka.y, a);
    a = fmaf(qa.z, ka.z, a);
    a = fmaf(qa.w, ka.w, a);
  }
  ws[WS_SC + i] = a;
}

// ---- shared row computation (weights via scalar/SMEM path) ----
__device__ __forceinline__ void compute_row(
    const int t, const int* toks,
    const float* __restrict__ ws,
    const float* __restrict__ W1p, const float* __restrict__ W2p,
    const float* __restrict__ Wop, float* __restrict__ dst) {
  cfloat* W1 = to_const(W1p);
  cfloat* W2 = to_const(W2p);
  cfloat* Wo = to_const(Wop);

  const int tok_t = toks[t];
  const float* SC = ws + WS_SC + (t * NTOK + tok_t) * NROW;
  float sc[T];
#pragma unroll
  for (int s = 0; s < T; ++s)
    sc[s] = (s <= t) ? SC[s * NTOK + toks[s]] : -INFINITY;

  float mx = -INFINITY;
#pragma unroll
  for (int s = 0; s < T; ++s) mx = fmaxf(mx, sc[s]);
  float p[T];
  float den = 0.f;
#pragma unroll
  for (int s = 0; s < T; ++s) {
    p[s] = (s <= t) ? __expf(sc[s] - mx) : 0.f;
    den += p[s];
  }
  const float inv = 1.f / den;

  float o[D];
#pragma unroll
  for (int d = 0; d < D; ++d) o[d] = 0.f;
#pragma unroll
  for (int s = 0; s < T; ++s) {
    if (s <= t) {
      const float4* vr = (const float4*)(ws + WS_V + (s * NTOK + toks[s]) * D);
      const float ps = p[s];
#pragma unroll
      for (int g = 0; g < D / 4; ++g) {
        const float4 v4 = vr[g];
        o[4 * g + 0] = fmaf(ps, v4.x, o[4 * g + 0]);
        o[4 * g + 1] = fmaf(ps, v4.y, o[4 * g + 1]);
        o[4 * g + 2] = fmaf(ps, v4.z, o[4 * g + 2]);
        o[4 * g + 3] = fmaf(ps, v4.w, o[4 * g + 3]);
      }
    }
  }
  {
    const float4* xr = (const float4*)(ws + WS_X + (t * NTOK + tok_t) * D);
#pragma unroll
    for (int g = 0; g < D / 4; ++g) {
      const float4 x4 = xr[g];
      o[4 * g + 0] = fmaf(o[4 * g + 0], inv, x4.x);
      o[4 * g + 1] = fmaf(o[4 * g + 1], inv, x4.y);
      o[4 * g + 2] = fmaf(o[4 * g + 2], inv, x4.z);
      o[4 * g + 3] = fmaf(o[4 * g + 3], inv, x4.w);
    }
  }

  // LayerNorm 1
  {
    float s1 = 0.f;
#pragma unroll
    for (int d = 0; d < D; ++d) s1 += o[d];
    const float mean = s1 * (1.f / D);
    float s2 = 0.f;
#pragma unroll
    for (int d = 0; d < D; ++d) { const float c = o[d] - mean; s2 = fmaf(c, c, s2); }
    const float rr = rsqrtf(s2 * (1.f / D) + EPS);
#pragma unroll
    for (int d = 0; d < D; ++d) o[d] = (o[d] - mean) * rr;
  }

  // MLP (weights stream through the scalar pipe)
  float y[D];
#pragma unroll
  for (int d = 0; d < D; ++d) y[d] = 0.f;
#pragma unroll
  for (int jc = 0; jc < H / 16; ++jc) {
    float hh[16];
#pragma unroll
    for (int jj = 0; jj < 16; ++jj) {
      const int j = jc * 16 + jj;
      float a = 0.f;
#pragma unroll
      for (int d = 0; d < D; ++d) a = fmaf(o[d], W1[d * H + j], a);
      hh[jj] = fmaxf(a, 0.f);
    }
#pragma unroll
    for (int jj = 0; jj < 16; ++jj) {
      const int j = jc * 16 + jj;
#pragma unroll
      for (int d = 0; d < D; ++d) y[d] = fmaf(hh[jj], W2[j * D + d], y[d]);
    }
  }

  // residual + LayerNorm 2
#pragma unroll
  for (int d = 0; d < D; ++d) y[d] += o[d];
  {
    float s1 = 0.f;
#pragma unroll
    for (int d = 0; d < D; ++d) s1 += y[d];
    const float mean = s1 * (1.f / D);
    float s2 = 0.f;
#pragma unroll
    for (int d = 0; d < D; ++d) { const float c = y[d] - mean; s2 = fmaf(c, c, s2); }
    const float rr = rsqrtf(s2 * (1.f / D) + EPS);
#pragma unroll
    for (int d = 0; d < D; ++d) y[d] = (y[d] - mean) * rr;
  }

  // output projection (scalar-pipe weights)
#pragma unroll
  for (int v = 0; v < V; ++v) {
    float a = 0.f;
#pragma unroll
    for (int d = 0; d < D; ++d) a = fmaf(y[d], Wo[d * V + v], a);
    dst[v] = a;
  }
}

// ---- kernel C: fused main (t in [3,8), t-major) + prefix-table build ----
__global__ __launch_bounds__(256) void fused_main_kernel(
    const int* __restrict__ tokens,
    float* __restrict__ ws,
    const float* __restrict__ W1, const float* __restrict__ W2,
    const float* __restrict__ Wo, float* __restrict__ out) {
  if (blockIdx.x < MAIN_BLOCKS) {
    const int idx = blockIdx.x * 256 + threadIdx.x;   // [0, 5*BTOT), exact
    const int t = 3 + (idx >> 17);                    // wave-uniform (BTOT=2^17)
    const int b = idx & (BTOT - 1);
    const int4 ta = *(const int4*)(tokens + b * T);
    const int4 tb = *(const int4*)(tokens + b * T + 4);
    int toks[T];
    toks[0] = ta.x; toks[1] = ta.y; toks[2] = ta.z; toks[3] = ta.w;
    toks[4] = tb.x; toks[5] = tb.y; toks[6] = tb.z; toks[7] = tb.w;
    compute_row(t, toks, ws, W1, W2, Wo, out + (long long)(b * T + t) * V);
  } else {
    const int i = (blockIdx.x - MAIN_BLOCKS) * 256 + threadIdx.x;
    if (i >= NPRE) return;
    int t, p;
    if (i < NPRE0)              { t = 0; p = i; }
    else if (i < NPRE0 + NPRE1) { t = 1; p = i - NPRE0; }
    else                        { t = 2; p = i - NPRE0 - NPRE1; }
    int toks[T] = {0, 0, 0, 0, 0, 0, 0, 0};
    if (t == 0) { toks[0] = p; }
    else if (t == 1) { toks[0] = p / 27; toks[1] = p % 27; }
    else { toks[0] = p / 729; const int r = p % 729; toks[1] = r / 27; toks[2] = r % 27; }
    compute_row(t, toks, ws, W1, W2, Wo, ws + WS_P + i * V);
  }
}

// ---- kernel G: gather t<=2 rows; thread per (b, r) with r in [0,81) so
//      each b's three output rows are one contiguous 324B write run ----
__global__ __launch_bounds__(256) void gather_kernel(
    const int* __restrict__ tokens,
    const float* __restrict__ ws,
    float* __restrict__ out) {
  const int idx = blockIdx.x * 256 + threadIdx.x;   // [0, BTOT*81), exact
  const int b = idx / 81;
  const int r = idx - b * 81;
  const int t = r / 27;
  const int j = r - t * 27;
  const int t0 = tokens[b * T + 0];
  const int t1 = tokens[b * T + 1];
  const int t2 = tokens[b * T + 2];
  const int p01 = t0 * 27 + t1;
  const int pi = (t == 0) ? t0
               : (t == 1) ? (NPRE0 + p01)
                          : (NPRE0 + NPRE1 + p01 * 27 + t2);
  out[(long long)b * (T * V) + r] = ws[WS_P + pi * V + j];
}

// ---- fallback (R4-style): all rows, r-major ----
__global__ __launch_bounds__(256) void mini_kernel_all(
    const int* __restrict__ tokens,
    const float* __restrict__ ws,
    const float* __restrict__ W1, const float* __restrict__ W2,
    const float* __restrict__ Wo, float* __restrict__ out) {
  const int r = blockIdx.x * 256 + threadIdx.x;
  const int b = r >> 3;
  const int t = r & 7;
  const int4 ta = *(const int4*)(tokens + b * T);
  const int4 tb = *(const int4*)(tokens + b * T + 4);
  int toks[T];
  toks[0] = ta.x; toks[1] = ta.y; toks[2] = ta.z; toks[3] = ta.w;
  toks[4] = tb.x; toks[5] = tb.y; toks[6] = tb.z; toks[7] = tb.w;
  compute_row(t, toks, ws, W1, W2, Wo, out + (long long)r * V);
}

extern "C" void kernel_launch(void* const* d_in, const int* in_sizes, int n_in,
                              void* d_out, int out_size, void* d_ws, size_t ws_size,
                              hipStream_t stream) {
  const int*   tokens  = (const int*)d_in[0];
  const float* tok_emb = (const float*)d_in[1];
  const float* pos_emb = (const float*)d_in[2];
  const float* Wq      = (const float*)d_in[3];
  const float* Wk      = (const float*)d_in[4];
  const float* Wv      = (const float*)d_in[5];
  const float* W1      = (const float*)d_in[6];
  const float* W2      = (const float*)d_in[7];
  const float* Wout    = (const float*)d_in[8];
  float* ws = (float*)d_ws;
  float* out = (float*)d_out;

  hipLaunchKernelGGL(build_rows_kernel, dim3((NROW * D + 255) / 256), dim3(256), 0,
                     stream, tok_emb, pos_emb, Wq, Wk, Wv, ws);
  hipLaunchKernelGGL(build_sc_kernel, dim3((NSC + 255) / 256), dim3(256), 0, stream, ws);

  if (ws_size >= WS_NEED_BIG) {
    hipLaunchKernelGGL(fused_main_kernel, dim3(MAIN_BLOCKS + PRE_BLOCKS), dim3(256), 0,
                       stream, tokens, ws, W1, W2, Wout, out);
    hipLaunchKernelGGL(gather_kernel, dim3((BTOT * 81) / 256), dim3(256), 0, stream,
                       tokens, ws, out);
  } else {
    hipLaunchKernelGGL(mini_kernel_all, dim3((BTOT * T) / 256), dim3(256), 0,
                       stream, tokens, ws, W1, W2, Wout, out);
  }
}

// Round 5
// 329.606 us; speedup vs baseline: 1.1474x; 1.1474x over previous
//
#include <hip/hip_runtime.h>

// MiniTransformer: B=131072, T=8, D=32, H=64, V=27  (all f32, out f32)
// R11: LDS weights, spill-proof j-major MLP.
//   Model (R6..R10 data): fused_main is latency-bound on ~3.4k wave-uniform
//   weight loads/wave that thrash past the 32KB L1 (SC/V/X gather traffic
//   evicts the 19.8KB of weights) => ~200cy L2 latency with only ~3
//   waves/SIMD to hide it. R7 proved LDS weights remove ~5k instr/wave but
//   died on spills (live set ~115 regs: hh[16]+o[32]+y[32]+4 quads).
//   R11 restructures the MLP j-major over transposed W1: per j, h_j =
//   dot(o, W1T[j]) via 4 partials, relu, then y += h_j*W2[j][:]. No hh
//   array, <=2 quads in flight => live ~80 regs, no launch-bounds games
//   (R8 lesson: min-waves TIGHTENS the allocator on this toolchain).
//   Tell for failure: WRITE_SIZE >> 75MB means it spilled => revert.

namespace {
constexpr int BTOT = 131072;     // 2^17
constexpr int T = 8;
constexpr int D = 32;
constexpr int H = 64;
constexpr int V = 27;
constexpr int NTOK = 27;
constexpr int NROW = T * NTOK;   // 216
constexpr float EPS = 1e-5f;

// ws layout (float offsets)
constexpr int WS_X  = 0;             // 216*32
constexpr int WS_Q  = 6912;
constexpr int WS_K  = 13824;
constexpr int WS_V  = 20736;
constexpr int WS_SC = 27648;         // 216*216 = 46656
constexpr int NSC   = NROW * NROW;
constexpr int WS_P  = WS_SC + NSC;   // 74304: prefix-output tables
constexpr int NPRE0 = 27;
constexpr int NPRE1 = 729;
constexpr int NPRE2 = 19683;
constexpr int NPRE  = NPRE0 + NPRE1 + NPRE2;   // 20439
constexpr size_t WS_NEED_BIG = (size_t)(WS_P + NPRE * V) * 4;  // ~2.45 MB

constexpr int MAIN_BLOCKS = (5 * BTOT) / 256;          // 2560, exact
constexpr int PRE_BLOCKS  = (NPRE + 255) / 256;        // 80
} // namespace

// ---- kernel A: X/Q/K/V row tables, thread per (row,d) ----
__global__ __launch_bounds__(256) void build_rows_kernel(
    const float* __restrict__ tokE, const float* __restrict__ posE,
    const float* __restrict__ Wq, const float* __restrict__ Wk,
    const float* __restrict__ Wv, float* __restrict__ ws) {
  const int idx = blockIdx.x * 256 + threadIdx.x;
  if (idx >= NROW * D) return;
  const int row = idx >> 5, d = idx & 31;
  const int t = row / NTOK, tok = row % NTOK;
  float x[D];
#pragma unroll
  for (int g = 0; g < D / 4; ++g) {
    const float4 a = *(const float4*)(tokE + tok * D + 4 * g);
    const float4 c = *(const float4*)(posE + t * D + 4 * g);
    x[4 * g + 0] = a.x + c.x;
    x[4 * g + 1] = a.y + c.y;
    x[4 * g + 2] = a.z + c.z;
    x[4 * g + 3] = a.w + c.w;
  }
  float aq = 0.f, ak = 0.f, av = 0.f;
#pragma unroll
  for (int k = 0; k < D; ++k) {
    const float xv = x[k];
    aq = fmaf(xv, Wq[k * D + d], aq);
    ak = fmaf(xv, Wk[k * D + d], ak);
    av = fmaf(xv, Wv[k * D + d], av);
  }
  ws[WS_X + row * D + d] = x[d];
  ws[WS_Q + row * D + d] = aq;
  ws[WS_K + row * D + d] = ak;
  ws[WS_V + row * D + d] = av;
}

// ---- kernel B: score table SC[(t*27+tokt)*216 + s*27+toks] ----
__global__ __launch_bounds__(256) void build_sc_kernel(float* __restrict__ ws) {
  const int i = blockIdx.x * 256 + threadIdx.x;
  if (i >= NSC) return;
  const int qrow = i / NROW;
  const int j    = i - qrow * NROW;
  const float4* q = (const float4*)(ws + WS_Q + qrow * D);
  const float4* k = (const float4*)(ws + WS_K + j * D);
  float a = 0.f;
#pragma unroll
  for (int g = 0; g < D / 4; ++g) {
    const float4 qa = q[g], ka = k[g];
    a = fmaf(qa.x, ka.x, a);
    a = fmaf(qa.y, ka.y, a);
    a = fmaf(qa.z, ka.z, a);
    a = fmaf(qa.w, ka.w, a);
  }
  ws[WS_SC + i] = a;
}

// ---- shared row computation (weights from LDS, j-major MLP) ----
// sW1T[j*32+d] = W1[d][j]; sW2[j*32+d] = W2[j][d]; sWoT[v*32+d] = Wo[d][v]
__device__ __forceinline__ void compute_row(
    const int t, const int* toks,
    const float* __restrict__ ws,
    const float* sW1T, const float* sW2, const float* sWoT,
    float* __restrict__ dst) {
  const int tok_t = toks[t];
  const float* SC = ws + WS_SC + (t * NTOK + tok_t) * NROW;
  float sc[T];
#pragma unroll
  for (int s = 0; s < T; ++s)
    sc[s] = (s <= t) ? SC[s * NTOK + toks[s]] : -INFINITY;

  // tree max
  const float m01 = fmaxf(sc[0], sc[1]), m23 = fmaxf(sc[2], sc[3]);
  const float m45 = fmaxf(sc[4], sc[5]), m67 = fmaxf(sc[6], sc[7]);
  const float mx = fmaxf(fmaxf(m01, m23), fmaxf(m45, m67));

  float p[T];
  float den0 = 0.f, den1 = 0.f;
#pragma unroll
  for (int s = 0; s < T; s += 2) {
    p[s]     = (s     <= t) ? __expf(sc[s]     - mx) : 0.f;
    p[s + 1] = (s + 1 <= t) ? __expf(sc[s + 1] - mx) : 0.f;
    den0 += p[s];
    den1 += p[s + 1];
  }
  const float inv = 1.f / (den0 + den1);

  float o[D];
#pragma unroll
  for (int d = 0; d < D; ++d) o[d] = 0.f;
#pragma unroll
  for (int s = 0; s < T; ++s) {
    if (s <= t) {
      const float4* vr = (const float4*)(ws + WS_V + (s * NTOK + toks[s]) * D);
      const float ps = p[s];
#pragma unroll
      for (int g = 0; g < D / 4; ++g) {
        const float4 v4 = vr[g];
        o[4 * g + 0] = fmaf(ps, v4.x, o[4 * g + 0]);
        o[4 * g + 1] = fmaf(ps, v4.y, o[4 * g + 1]);
        o[4 * g + 2] = fmaf(ps, v4.z, o[4 * g + 2]);
        o[4 * g + 3] = fmaf(ps, v4.w, o[4 * g + 3]);
      }
    }
  }
  {
    const float4* xr = (const float4*)(ws + WS_X + (t * NTOK + tok_t) * D);
#pragma unroll
    for (int g = 0; g < D / 4; ++g) {
      const float4 x4 = xr[g];
      o[4 * g + 0] = fmaf(o[4 * g + 0], inv, x4.x);
      o[4 * g + 1] = fmaf(o[4 * g + 1], inv, x4.y);
      o[4 * g + 2] = fmaf(o[4 * g + 2], inv, x4.z);
      o[4 * g + 3] = fmaf(o[4 * g + 3], inv, x4.w);
    }
  }

  // LayerNorm 1 (4-accumulator trees)
  {
    float s1a = 0.f, s1b = 0.f, s1c = 0.f, s1d = 0.f;
#pragma unroll
    for (int d = 0; d < D; d += 4) {
      s1a += o[d]; s1b += o[d + 1]; s1c += o[d + 2]; s1d += o[d + 3];
    }
    const float mean = ((s1a + s1b) + (s1c + s1d)) * (1.f / D);
    float q0 = 0.f, q1 = 0.f, q2 = 0.f, q3 = 0.f;
#pragma unroll
    for (int d = 0; d < D; d += 4) {
      const float c0 = o[d] - mean, c1 = o[d + 1] - mean;
      const float c2 = o[d + 2] - mean, c3 = o[d + 3] - mean;
      q0 = fmaf(c0, c0, q0); q1 = fmaf(c1, c1, q1);
      q2 = fmaf(c2, c2, q2); q3 = fmaf(c3, c3, q3);
    }
    const float rr = rsqrtf(((q0 + q1) + (q2 + q3)) * (1.f / D) + EPS);
#pragma unroll
    for (int d = 0; d < D; ++d) o[d] = (o[d] - mean) * rr;
  }

  // MLP j-major: per j, h_j from W1T row (broadcast ds_read_b128),
  // relu, immediate y-accumulate from W2 row. No hh[] array.
  float y[D];
#pragma unroll
  for (int d = 0; d < D; ++d) y[d] = 0.f;
#pragma unroll
  for (int j = 0; j < H; ++j) {
    const float4* w1r = (const float4*)(sW1T + j * D);
    float a0 = 0.f, a1 = 0.f, a2 = 0.f, a3 = 0.f;
#pragma unroll
    for (int g = 0; g < 8; ++g) {
      const float4 w = w1r[g];
      a0 = fmaf(o[4 * g + 0], w.x, a0);
      a1 = fmaf(o[4 * g + 1], w.y, a1);
      a2 = fmaf(o[4 * g + 2], w.z, a2);
      a3 = fmaf(o[4 * g + 3], w.w, a3);
    }
    const float hj = fmaxf((a0 + a1) + (a2 + a3), 0.f);
    const float4* w2r = (const float4*)(sW2 + j * D);
#pragma unroll
    for (int g = 0; g < 8; ++g) {
      const float4 w = w2r[g];
      y[4 * g + 0] = fmaf(hj, w.x, y[4 * g + 0]);
      y[4 * g + 1] = fmaf(hj, w.y, y[4 * g + 1]);
      y[4 * g + 2] = fmaf(hj, w.z, y[4 * g + 2]);
      y[4 * g + 3] = fmaf(hj, w.w, y[4 * g + 3]);
    }
  }

  // residual + LayerNorm 2
#pragma unroll
  for (int d = 0; d < D; ++d) y[d] += o[d];
  {
    float s1a = 0.f, s1b = 0.f, s1c = 0.f, s1d = 0.f;
#pragma unroll
    for (int d = 0; d < D; d += 4) {
      s1a += y[d]; s1b += y[d + 1]; s1c += y[d + 2]; s1d += y[d + 3];
    }
    const float mean = ((s1a + s1b) + (s1c + s1d)) * (1.f / D);
    float q0 = 0.f, q1 = 0.f, q2 = 0.f, q3 = 0.f;
#pragma unroll
    for (int d = 0; d < D; d += 4) {
      const float c0 = y[d] - mean, c1 = y[d + 1] - mean;
      const float c2 = y[d + 2] - mean, c3 = y[d + 3] - mean;
      q0 = fmaf(c0, c0, q0); q1 = fmaf(c1, c1, q1);
      q2 = fmaf(c2, c2, q2); q3 = fmaf(c3, c3, q3);
    }
    const float rr = rsqrtf(((q0 + q1) + (q2 + q3)) * (1.f / D) + EPS);
#pragma unroll
    for (int d = 0; d < D; ++d) y[d] = (y[d] - mean) * rr;
  }

  // output projection from transposed Wout in LDS
#pragma unroll
  for (int v = 0; v < V; ++v) {
    const float4* wr = (const float4*)(sWoT + v * D);
    float a0 = 0.f, a1 = 0.f, a2 = 0.f, a3 = 0.f;
#pragma unroll
    for (int g = 0; g < 8; ++g) {
      const float4 w = wr[g];
      a0 = fmaf(y[4 * g + 0], w.x, a0);
      a1 = fmaf(y[4 * g + 1], w.y, a1);
      a2 = fmaf(y[4 * g + 2], w.z, a2);
      a3 = fmaf(y[4 * g + 3], w.w, a3);
    }
    dst[v] = (a0 + a1) + (a2 + a3);
  }
}

// ---- weight staging into LDS (W1 and Wout transposed) ----
__device__ __forceinline__ void stage_weights(
    const float* __restrict__ W1, const float* __restrict__ W2,
    const float* __restrict__ Wo,
    float* sW1T, float* sW2, float* sWoT) {
  const int tid = threadIdx.x;
  for (int i = tid; i < D * H; i += 256) {
    const int j = i >> 5, d = i & 31;           // i = j*32 + d
    sW1T[i] = W1[d * H + j];
  }
#pragma unroll
  for (int i = tid; i < (H * D) / 4; i += 256)
    ((float4*)sW2)[i] = ((const float4*)W2)[i];
  for (int i = tid; i < V * D; i += 256) {
    const int v = i >> 5, d = i & 31;           // i = v*32 + d
    sWoT[i] = Wo[d * V + v];
  }
  __syncthreads();
}

// ---- kernel C: fused main (t in [3,8), t-major) + prefix-table build ----
__global__ __launch_bounds__(256) void fused_main_kernel(
    const int* __restrict__ tokens,
    float* __restrict__ ws,
    const float* __restrict__ W1, const float* __restrict__ W2,
    const float* __restrict__ Wo, float* __restrict__ out) {
  __shared__ float sW1T[H * D];   // 8 KB, transposed
  __shared__ float sW2[H * D];    // 8 KB
  __shared__ float sWoT[V * D];   // 3.4 KB, transposed
  stage_weights(W1, W2, Wo, sW1T, sW2, sWoT);

  if (blockIdx.x < MAIN_BLOCKS) {
    const int idx = blockIdx.x * 256 + threadIdx.x;   // [0, 5*BTOT), exact
    const int t = 3 + (idx >> 17);                    // wave-uniform (BTOT=2^17)
    const int b = idx & (BTOT - 1);
    const int4 ta = *(const int4*)(tokens + b * T);
    const int4 tb = *(const int4*)(tokens + b * T + 4);
    int toks[T];
    toks[0] = ta.x; toks[1] = ta.y; toks[2] = ta.z; toks[3] = ta.w;
    toks[4] = tb.x; toks[5] = tb.y; toks[6] = tb.z; toks[7] = tb.w;
    compute_row(t, toks, ws, sW1T, sW2, sWoT, out + (long long)(b * T + t) * V);
  } else {
    const int i = (blockIdx.x - MAIN_BLOCKS) * 256 + threadIdx.x;
    if (i >= NPRE) return;
    int t, p;
    if (i < NPRE0)              { t = 0; p = i; }
    else if (i < NPRE0 + NPRE1) { t = 1; p = i - NPRE0; }
    else                        { t = 2; p = i - NPRE0 - NPRE1; }
    int toks[T] = {0, 0, 0, 0, 0, 0, 0, 0};
    if (t == 0) { toks[0] = p; }
    else if (t == 1) { toks[0] = p / 27; toks[1] = p % 27; }
    else { toks[0] = p / 729; const int r = p % 729; toks[1] = r / 27; toks[2] = r % 27; }
    compute_row(t, toks, ws, sW1T, sW2, sWoT, ws + WS_P + i * V);
  }
}

// ---- kernel G: gather t<=2 rows; thread per (b, r), r in [0,81):
//      each b's three output rows are one contiguous 324B write run ----
__global__ __launch_bounds__(256) void gather_kernel(
    const int* __restrict__ tokens,
    const float* __restrict__ ws,
    float* __restrict__ out) {
  const int idx = blockIdx.x * 256 + threadIdx.x;   // [0, BTOT*81), exact
  const int b = idx / 81;
  const int r = idx - b * 81;
  const int t = r / 27;
  const int j = r - t * 27;
  const int t0 = tokens[b * T + 0];
  const int t1 = tokens[b * T + 1];
  const int t2 = tokens[b * T + 2];
  const int p01 = t0 * 27 + t1;
  const int pi = (t == 0) ? t0
               : (t == 1) ? (NPRE0 + p01)
                          : (NPRE0 + NPRE1 + p01 * 27 + t2);
  out[(long long)b * (T * V) + r] = ws[WS_P + pi * V + j];
}

// ---- fallback (R4-style): all rows, r-major ----
__global__ __launch_bounds__(256) void mini_kernel_all(
    const int* __restrict__ tokens,
    const float* __restrict__ ws,
    const float* __restrict__ W1, const float* __restrict__ W2,
    const float* __restrict__ Wo, float* __restrict__ out) {
  __shared__ float sW1T[H * D];
  __shared__ float sW2[H * D];
  __shared__ float sWoT[V * D];
  stage_weights(W1, W2, Wo, sW1T, sW2, sWoT);

  const int r = blockIdx.x * 256 + threadIdx.x;
  const int b = r >> 3;
  const int t = r & 7;
  const int4 ta = *(const int4*)(tokens + b * T);
  const int4 tb = *(const int4*)(tokens + b * T + 4);
  int toks[T];
  toks[0] = ta.x; toks[1] = ta.y; toks[2] = ta.z; toks[3] = ta.w;
  toks[4] = tb.x; toks[5] = tb.y; toks[6] = tb.z; toks[7] = tb.w;
  compute_row(t, toks, ws, sW1T, sW2, sWoT, out + (long long)r * V);
}

extern "C" void kernel_launch(void* const* d_in, const int* in_sizes, int n_in,
                              void* d_out, int out_size, void* d_ws, size_t ws_size,
                              hipStream_t stream) {
  const int*   tokens  = (const int*)d_in[0];
  const float* tok_emb = (const float*)d_in[1];
  const float* pos_emb = (const float*)d_in[2];
  const float* Wq      = (const float*)d_in[3];
  const float* Wk      = (const float*)d_in[4];
  const float* Wv      = (const float*)d_in[5];
  const float* W1      = (const float*)d_in[6];
  const float* W2      = (const float*)d_in[7];
  const float* Wout    = (const float*)d_in[8];
  float* ws = (float*)d_ws;
  float* out = (float*)d_out;

  hipLaunchKernelGGL(build_rows_kernel, dim3((NROW * D + 255) / 256), dim3(256), 0,
                     stream, tok_emb, pos_emb, Wq, Wk, Wv, ws);
  hipLaunchKernelGGL(build_sc_kernel, dim3((NSC + 255) / 256), dim3(256), 0, stream, ws);

  if (ws_size >= WS_NEED_BIG) {
    hipLaunchKernelGGL(fused_main_kernel, dim3(MAIN_BLOCKS + PRE_BLOCKS), dim3(256), 0,
                       stream, tokens, ws, W1, W2, Wout, out);
    hipLaunchKernelGGL(gather_kernel, dim3((BTOT * 81) / 256), dim3(256), 0, stream,
                       tokens, ws, out);
  } else {
    hipLaunchKernelGGL(mini_kernel_all, dim3((BTOT * T) / 256), dim3(256), 0,
                       stream, tokens, ws, W1, W2, Wout, out);
  }
}